// Round 8
// baseline (197.040 us; speedup 1.0000x reference)
//
#include <hip/hip_runtime.h>

typedef unsigned short u16;
typedef short bf16x8 __attribute__((ext_vector_type(8)));
typedef float f32x4 __attribute__((ext_vector_type(4)));

#define DEVINL __device__ __forceinline__

// fp32 -> bf16 (round-to-nearest-even), bit-level
DEVINL u16 f2bf(float f) {
    union { float f; unsigned int u; } x;
    x.f = f;
    unsigned int u = x.u;
    unsigned int r = (u + 0x7fffu + ((u >> 16) & 1u)) >> 16;
    return (u16)r;
}

// fast fp32 -> bf16 (round-half-up); used for P (bounded, positive) only
DEVINL u16 f2bf_fast(float f) {
    union { float f; unsigned int u; } x;
    x.f = f;
    return (u16)((x.u + 0x8000u) >> 16);
}

// async global->LDS, 16 bytes per lane.
DEVINL void async16(const u16* g, u16* l) {
    __builtin_amdgcn_global_load_lds(
        (const __attribute__((address_space(1))) void*)g,
        (__attribute__((address_space(3))) void*)l, 16, 0, 0);
}

// store helpers: bf16 intermediate vs fp32 final output
DEVINL void store_out(u16* p, float v)   { *p = f2bf(v); }
DEVINL void store_out(float* p, float v) { *p = v; }

// ---------------------------------------------------------------------------
// fp32 -> bf16 convert, vectorized
// ---------------------------------------------------------------------------
__global__ void pma_cvt_kernel(const float* __restrict__ in, u16* __restrict__ out, int n4) {
    int i = blockIdx.x * blockDim.x + threadIdx.x;
    if (i < n4) {
        float4 v = reinterpret_cast<const float4*>(in)[i];
        ushort4 o;
        o.x = f2bf(v.x); o.y = f2bf(v.y); o.z = f2bf(v.z); o.w = f2bf(v.w);
        reinterpret_cast<ushort4*>(out)[i] = o;
    }
}

// 4 weight matrices in one launch; Wq (wsel==0) pre-scaled by 1/8 (= 1/sqrt(64), exact).
__global__ void pma_cvt4_kernel(const float* __restrict__ w0, const float* __restrict__ w1,
                                const float* __restrict__ w2, const float* __restrict__ w3,
                                u16* __restrict__ dst) {
    const int wsel = blockIdx.y;
    const float* in = (wsel == 0) ? w0 : (wsel == 1) ? w1 : (wsel == 2) ? w2 : w3;
    u16* out = dst + (size_t)wsel * 1024 * 1024;
    const float s = (wsel == 0) ? 0.125f : 1.0f;
    int i = blockIdx.x * blockDim.x + threadIdx.x;
    float4 v = reinterpret_cast<const float4*>(in)[i];
    ushort4 o;
    o.x = f2bf(v.x * s); o.y = f2bf(v.y * s); o.z = f2bf(v.z * s); o.w = f2bf(v.w * s);
    reinterpret_cast<ushort4*>(out)[i] = o;
}

// ---------------------------------------------------------------------------
// GEMM: O[m][n] = sum_k A[m][k] * W[n][k], bf16 in, f32 acc, 128x128 tile.
// which == vtr_which (bf16 out only): store transposed into [bh*64+d][2048 s].
// ---------------------------------------------------------------------------
template <typename OutT>
__global__ __launch_bounds__(256) void pma_gemm_bt(
    const u16* __restrict__ A,
    const u16* __restrict__ W0, const u16* __restrict__ W1, const u16* __restrict__ W2,
    OutT* __restrict__ O0, OutT* __restrict__ O1, OutT* __restrict__ O2,
    int K, int nbn_per, int vtr_which)
{
    const int t = threadIdx.x;
    const int lane = t & 63, wave = t >> 6;
    const int m0 = blockIdx.x * 128;
    const int bn = blockIdx.y;
    const int which = bn / nbn_per;
    const int n0 = (bn % nbn_per) * 128;
    const u16* W = (which == 0) ? W0 : (which == 1) ? W1 : W2;
    OutT* O = (which == 0) ? O0 : (which == 1) ? O1 : O2;

    __shared__ u16 Alds[128 * 32];
    __shared__ u16 Blds[128 * 32];

    const int wm = wave >> 1, wn = wave & 1;
    const int r16 = lane & 15, g4 = lane >> 4;

    f32x4 acc[4][4];
    const f32x4 z = {0.f, 0.f, 0.f, 0.f};
#pragma unroll
    for (int m = 0; m < 4; ++m)
#pragma unroll
        for (int n = 0; n < 4; ++n) acc[m][n] = z;

    for (int k0 = 0; k0 < K; k0 += 32) {
        __syncthreads();
#pragma unroll
        for (int j = 0; j < 2; ++j) {
            int i = j * 256 + t;
            int row = i >> 2, seg = i & 3;
            async16(A + (size_t)(m0 + row) * K + k0 + seg * 8,
                    Alds + (size_t)(j * 256 + wave * 64) * 8);
            async16(W + (size_t)(n0 + row) * K + k0 + seg * 8,
                    Blds + (size_t)(j * 256 + wave * 64) * 8);
        }
        __syncthreads();

        bf16x8 af[4], bfr[4];
#pragma unroll
        for (int m = 0; m < 4; ++m)
            af[m] = *reinterpret_cast<const bf16x8*>(Alds + (wm * 64 + m * 16 + r16) * 32 + g4 * 8);
#pragma unroll
        for (int n = 0; n < 4; ++n)
            bfr[n] = *reinterpret_cast<const bf16x8*>(Blds + (wn * 64 + n * 16 + r16) * 32 + g4 * 8);
#pragma unroll
        for (int m = 0; m < 4; ++m)
#pragma unroll
            for (int n = 0; n < 4; ++n)
                acc[m][n] = __builtin_amdgcn_mfma_f32_16x16x32_bf16(af[m], bfr[n], acc[m][n], 0, 0, 0);
    }

    // epilogue: C/D layout col = lane&15, row = (lane>>4)*4 + reg
    bool vtr = false;
    if constexpr (sizeof(OutT) == 2) vtr = (which == vtr_which);
    if (vtr) {
        if constexpr (sizeof(OutT) == 2) {
#pragma unroll
            for (int m = 0; m < 4; ++m)
#pragma unroll
                for (int n = 0; n < 4; ++n) {
                    int row = m0 + wm * 64 + m * 16 + g4 * 4;
                    int col = n0 + wn * 64 + n * 16 + r16;
                    ushort4 pk;
                    pk.x = f2bf(acc[m][n][0]); pk.y = f2bf(acc[m][n][1]);
                    pk.z = f2bf(acc[m][n][2]); pk.w = f2bf(acc[m][n][3]);
                    size_t addr = ((size_t)((row >> 11) * 16 + (col >> 6)) * 64 + (col & 63)) * 2048
                                  + (row & 2047);
                    *reinterpret_cast<ushort4*>((u16*)O + addr) = pk;
                }
        }
    } else {
#pragma unroll
        for (int m = 0; m < 4; ++m)
#pragma unroll
            for (int n = 0; n < 4; ++n) {
                int row = m0 + wm * 64 + m * 16 + g4 * 4;
                int col = n0 + wn * 64 + n * 16 + r16;
#pragma unroll
                for (int r = 0; r < 4; ++r)
                    store_out(&O[(size_t)(row + r) * 1024 + col], acc[m][n][r]);
            }
    }
}

// ---------------------------------------------------------------------------
// Flash attention (causal + padding), bf16 MFMA, fp32 accumulate.
// Barrier-free: K and V fragments read directly from global (L1/L2-hot);
// only P round-trips through per-wave-private LDS (wave-ordered DS ops).
// Co-resident blocks get qts {q,15-q,16+q,31-q} (balanced) with same (b,h)
// (cache locality). Swapped QK^T; T13 defer-rescale; exp2-domain softmax.
// ---------------------------------------------------------------------------
__global__ __launch_bounds__(256, 4) void pma_attn_kernel(
    const u16* __restrict__ Q, const u16* __restrict__ Kp, const u16* __restrict__ Vt,
    const int* __restrict__ seq_lengths, u16* __restrict__ O)
{
    const int bx = blockIdx.x;
    const int T = bx >> 5;               // 0..31 tile-slot
    const int a = T >> 3, qq = T & 7;    // co-res: same qq, a = 0..3
    const int qt = (a == 0) ? qq : (a == 1) ? (15 - qq) : (a == 2) ? (16 + qq) : (31 - qq);
    const int bh = bx & 31;
    const int h  = bh & 15;
    const int b  = bh >> 4;
    const int q0 = qt * 64;
    const int t = threadIdx.x, lane = t & 63, w = t >> 6;
    const int r16 = lane & 15, g4 = lane >> 4;
    const int seqlen = seq_lengths[b];
    const float L2E = 1.4426950408889634f;

    __shared__ u16 Plds[64 * 72];        // per-wave rows w*16..w*16+15

    const size_t bbase = (size_t)b * 2048 * 1024;
    const size_t hoff = (size_t)h * 64;
    const u16* Kbp = Kp + bbase + hoff;                       // row stride 1024
    const u16* Vbp = Vt + (size_t)((b * 16 + h) * 64) * 2048; // row stride 2048

    const f32x4 z = {0.f, 0.f, 0.f, 0.f};

    const size_t qrowbase = bbase + (size_t)(q0 + w * 16 + r16) * 1024 + hoff;
    const bf16x8 qf0 = *reinterpret_cast<const bf16x8*>(Q + qrowbase + g4 * 8);
    const bf16x8 qf1 = *reinterpret_cast<const bf16x8*>(Q + qrowbase + 32 + g4 * 8);

    f32x4 acc[4];
#pragma unroll
    for (int f = 0; f < 4; ++f) acc[f] = z;
    float mrow = -1e30f, lrow = 0.f;

    int kmax = q0 + 63;
    if (seqlen - 1 < kmax) kmax = seqlen - 1;
    const int nt = (kmax >> 6) + 1;

    const int qhat = q0 + w * 16 + r16;

    // per-lane fragment bases
    const u16* kfrag = Kbp + (size_t)r16 * 1024 + g4 * 8;   // + key*1024 (+32 for hi half)
    const u16* vfrag = Vbp + (size_t)r16 * 2048 + g4 * 8;   // + d16*16*2048 + key

    for (int tt = 0; tt < nt; ++tt) {
        const int t0 = tt << 6;

        // ---- scores (swapped): K fragments straight from global ----
        f32x4 sraw[4];
        __builtin_amdgcn_s_setprio(1);
#pragma unroll
        for (int kc = 0; kc < 4; ++kc) {
            const u16* kp = kfrag + (size_t)(t0 + kc * 16) * 1024;
            bf16x8 kf0 = *reinterpret_cast<const bf16x8*>(kp);
            bf16x8 kf1 = *reinterpret_cast<const bf16x8*>(kp + 32);
            f32x4 s = z;
            s = __builtin_amdgcn_mfma_f32_16x16x32_bf16(kf0, qf0, s, 0, 0, 0);
            s = __builtin_amdgcn_mfma_f32_16x16x32_bf16(kf1, qf1, s, 0, 0, 0);
            sraw[kc] = s;
        }
        __builtin_amdgcn_s_setprio(0);

        float sc[4][4];
        const bool needmask = (t0 == q0) || (t0 + 64 > seqlen);
        if (needmask) {
#pragma unroll
            for (int kc = 0; kc < 4; ++kc) {
                const int keyb = t0 + kc * 16 + g4 * 4;
#pragma unroll
                for (int r = 0; r < 4; ++r)
                    sc[kc][r] = ((keyb + r > qhat) || (keyb + r >= seqlen)) ? -1e30f : sraw[kc][r];
            }
        } else {
#pragma unroll
            for (int kc = 0; kc < 4; ++kc)
#pragma unroll
                for (int r = 0; r < 4; ++r) sc[kc][r] = sraw[kc][r];
        }

        // ---- online softmax (exp2 domain), T13 defer-rescale ----
        float mx;
        {
            float m0 = fmaxf(fmaxf(sc[0][0], sc[0][1]), fmaxf(sc[0][2], sc[0][3]));
            float m1 = fmaxf(fmaxf(sc[1][0], sc[1][1]), fmaxf(sc[1][2], sc[1][3]));
            float m2 = fmaxf(fmaxf(sc[2][0], sc[2][1]), fmaxf(sc[2][2], sc[2][3]));
            float m3 = fmaxf(fmaxf(sc[3][0], sc[3][1]), fmaxf(sc[3][2], sc[3][3]));
            mx = fmaxf(fmaxf(m0, m1), fmaxf(m2, m3));
        }
        mx = fmaxf(mx, __shfl_xor(mx, 16, 64));
        mx = fmaxf(mx, __shfl_xor(mx, 32, 64));

        const bool norescale = __all(mx <= mrow + 8.0f);  // P bounded by e^8
        float mnew, corr;
        if (norescale) { mnew = mrow; corr = 1.0f; }
        else           { mnew = fmaxf(mrow, mx); corr = exp2f((mrow - mnew) * L2E); }

        const float nb = mnew * L2E;
#pragma unroll
        for (int kc = 0; kc < 4; ++kc)
#pragma unroll
            for (int r = 0; r < 4; ++r)
                sc[kc][r] = exp2f(__builtin_fmaf(sc[kc][r], L2E, -nb));
        float rs;
        {
            float s0 = (sc[0][0] + sc[0][1]) + (sc[0][2] + sc[0][3]);
            float s1 = (sc[1][0] + sc[1][1]) + (sc[1][2] + sc[1][3]);
            float s2 = (sc[2][0] + sc[2][1]) + (sc[2][2] + sc[2][3]);
            float s3 = (sc[3][0] + sc[3][1]) + (sc[3][2] + sc[3][3]);
            rs = (s0 + s1) + (s2 + s3);
        }
        rs += __shfl_xor(rs, 16, 64);
        rs += __shfl_xor(rs, 32, 64);
        lrow = lrow * corr + rs;
        mrow = mnew;

        // ---- write P (bf16) 4x b64 (per-wave-private rows) ----
#pragma unroll
        for (int kc = 0; kc < 4; ++kc) {
            ushort4 pk;
            pk.x = f2bf_fast(sc[kc][0]); pk.y = f2bf_fast(sc[kc][1]);
            pk.z = f2bf_fast(sc[kc][2]); pk.w = f2bf_fast(sc[kc][3]);
            *reinterpret_cast<ushort4*>(Plds + (w * 16 + r16) * 72 + kc * 16 + g4 * 4) = pk;
        }
        __builtin_amdgcn_wave_barrier();   // order P write -> P read (same wave)

        // ---- rescale acc (skipped when max stable: the common case) ----
        if (!norescale) {
            float cr0 = __shfl(corr, g4 * 4 + 0, 64);
            float cr1 = __shfl(corr, g4 * 4 + 1, 64);
            float cr2 = __shfl(corr, g4 * 4 + 2, 64);
            float cr3 = __shfl(corr, g4 * 4 + 3, 64);
#pragma unroll
            for (int f = 0; f < 4; ++f) {
                f32x4 a2 = acc[f];
                a2[0] *= cr0; a2[1] *= cr1; a2[2] *= cr2; a2[3] *= cr3;
                acc[f] = a2;
            }
        }

        // ---- PV: O[q][d] += P[q][k] * V[k][d]; V fragments from global ----
        __builtin_amdgcn_s_setprio(1);
#pragma unroll
        for (int kc2 = 0; kc2 < 2; ++kc2) {
            bf16x8 pa = *reinterpret_cast<const bf16x8*>(Plds + (w * 16 + r16) * 72 + kc2 * 32 + g4 * 8);
#pragma unroll
            for (int f = 0; f < 4; ++f) {
                bf16x8 vb = *reinterpret_cast<const bf16x8*>(
                    vfrag + (size_t)(f * 16) * 2048 + t0 + kc2 * 32);
                acc[f] = __builtin_amdgcn_mfma_f32_16x16x32_bf16(pa, vb, acc[f], 0, 0, 0);
            }
        }
        __builtin_amdgcn_s_setprio(0);
    }

    // ---- epilogue: normalize and store ----
    {
        float lr0 = __shfl(lrow, g4 * 4 + 0, 64);
        float lr1 = __shfl(lrow, g4 * 4 + 1, 64);
        float lr2 = __shfl(lrow, g4 * 4 + 2, 64);
        float lr3 = __shfl(lrow, g4 * 4 + 3, 64);
        float lr[4] = {lr0, lr1, lr2, lr3};
#pragma unroll
        for (int f = 0; f < 4; ++f)
#pragma unroll
            for (int r = 0; r < 4; ++r) {
                int sr = q0 + w * 16 + g4 * 4 + r;
                float o = acc[f][r] / lr[r];
                O[bbase + (size_t)sr * 1024 + hoff + f * 16 + r16] = f2bf(o);
            }
    }
}

// ---------------------------------------------------------------------------
extern "C" void kernel_launch(void* const* d_in, const int* in_sizes, int n_in,
                              void* d_out, int out_size, void* d_ws, size_t ws_size,
                              hipStream_t stream) {
    const float* x   = (const float*)d_in[0];
    const int*   sql = (const int*)d_in[1];
    const float* Wq  = (const float*)d_in[2];
    const float* Wk  = (const float*)d_in[3];
    const float* Wv  = (const float*)d_in[4];
    const float* Wo  = (const float*)d_in[5];
    float* out = (float*)d_out;

    const size_t MB = 1024 * 1024;
    char* ws = (char*)d_ws;
    u16* xb   = (u16*)(ws + 0 * MB);
    u16* wqb  = (u16*)(ws + 8 * MB);
    u16* wkb  = (u16*)(ws + 10 * MB);
    u16* wvb  = (u16*)(ws + 12 * MB);
    u16* wob  = (u16*)(ws + 14 * MB);
    u16* Qb   = (u16*)(ws + 16 * MB);
    u16* Kb   = (u16*)(ws + 24 * MB);
    u16* Vtb  = (u16*)(ws + 32 * MB);  // V transposed layout [bh*64+d][2048]
    u16* attb = (u16*)(ws + 40 * MB);

    // 1) convert inputs to bf16 (Wq pre-scaled by 1/8)
    pma_cvt_kernel<<<4096, 256, 0, stream>>>(x, xb, 1048576);
    pma_cvt4_kernel<<<dim3(1024, 4), 256, 0, stream>>>(Wq, Wk, Wv, Wo, wqb);

    // 2) fused QKV projection; V written transposed (vtr_which = 2)
    pma_gemm_bt<u16><<<dim3(32, 24), 256, 0, stream>>>(xb, wqb, wkb, wvb, Qb, Kb, Vtb, 1024, 8, 2);

    // 3) flash attention: 1024 blocks, balanced co-residency, barrier-free
    pma_attn_kernel<<<1024, 256, 0, stream>>>(Qb, Kb, Vtb, sql, attb);

    // 4) output projection -> d_out (fp32)
    pma_gemm_bt<float><<<dim3(32, 8), 256, 0, stream>>>(attb, wob, wob, wob, out, out, out, 1024, 8, -1);
}

// Round 10
// 139.560 us; speedup vs baseline: 1.4119x; 1.4119x over previous
//
#include <hip/hip_runtime.h>

typedef unsigned short u16;
typedef short bf16x8 __attribute__((ext_vector_type(8)));
typedef short bf16x4 __attribute__((ext_vector_type(4)));
typedef float f32x4 __attribute__((ext_vector_type(4)));

#define DEVINL __device__ __forceinline__

// fp32 -> bf16 (round-to-nearest-even), bit-level
DEVINL u16 f2bf(float f) {
    union { float f; unsigned int u; } x;
    x.f = f;
    unsigned int u = x.u;
    unsigned int r = (u + 0x7fffu + ((u >> 16) & 1u)) >> 16;
    return (u16)r;
}

// fast fp32 -> bf16 (round-half-up); used for P (bounded, positive) only
DEVINL u16 f2bf_fast(float f) {
    union { float f; unsigned int u; } x;
    x.f = f;
    return (u16)((x.u + 0x8000u) >> 16);
}

// async global->LDS, 16 bytes per lane (GEMM staging).
DEVINL void async16(const u16* g, u16* l) {
    __builtin_amdgcn_global_load_lds(
        (const __attribute__((address_space(1))) void*)g,
        (__attribute__((address_space(3))) void*)l, 16, 0, 0);
}

DEVINL void store_out(u16* p, float v)   { *p = f2bf(v); }
DEVINL void store_out(float* p, float v) { *p = v; }

DEVINL f32x4 mfma32(bf16x8 a, bf16x8 b, f32x4 c) {
    return __builtin_amdgcn_mfma_f32_16x16x32_bf16(a, b, c, 0, 0, 0);
}
// 16x16x16 bf16 MFMA via inline asm (gfx950 ISA §10; A/B = 2 VGPR, C/D = 4)
DEVINL f32x4 mfma16(bf16x4 a, bf16x4 b, f32x4 c) {
    asm("v_mfma_f32_16x16x16_bf16 %0, %1, %2, %0" : "+v"(c) : "v"(a), "v"(b));
    return c;
}

// ---------------------------------------------------------------------------
// fp32 -> bf16 convert kernels
// ---------------------------------------------------------------------------
__global__ void pma_cvt_kernel(const float* __restrict__ in, u16* __restrict__ out, int n4) {
    int i = blockIdx.x * blockDim.x + threadIdx.x;
    if (i < n4) {
        float4 v = reinterpret_cast<const float4*>(in)[i];
        ushort4 o;
        o.x = f2bf(v.x); o.y = f2bf(v.y); o.z = f2bf(v.z); o.w = f2bf(v.w);
        reinterpret_cast<ushort4*>(out)[i] = o;
    }
}

__global__ void pma_cvt4_kernel(const float* __restrict__ w0, const float* __restrict__ w1,
                                const float* __restrict__ w2, const float* __restrict__ w3,
                                u16* __restrict__ dst) {
    const int wsel = blockIdx.y;
    const float* in = (wsel == 0) ? w0 : (wsel == 1) ? w1 : (wsel == 2) ? w2 : w3;
    u16* out = dst + (size_t)wsel * 1024 * 1024;
    const float s = (wsel == 0) ? 0.125f : 1.0f;   // fold 1/sqrt(64) into Wq
    int i = blockIdx.x * blockDim.x + threadIdx.x;
    float4 v = reinterpret_cast<const float4*>(in)[i];
    ushort4 o;
    o.x = f2bf(v.x * s); o.y = f2bf(v.y * s); o.z = f2bf(v.z * s); o.w = f2bf(v.w * s);
    reinterpret_cast<ushort4*>(out)[i] = o;
}

// ---------------------------------------------------------------------------
// GEMM: O[m][n] = sum_k A[m][k] * W[n][k], bf16 in, f32 acc, 128x128 tile.
// which == vtr_which (bf16 out only): store transposed into [bh*64+d][2048 s].
// ---------------------------------------------------------------------------
template <typename OutT>
__global__ __launch_bounds__(256) void pma_gemm_bt(
    const u16* __restrict__ A,
    const u16* __restrict__ W0, const u16* __restrict__ W1, const u16* __restrict__ W2,
    OutT* __restrict__ O0, OutT* __restrict__ O1, OutT* __restrict__ O2,
    int K, int nbn_per, int vtr_which)
{
    const int t = threadIdx.x;
    const int lane = t & 63, wave = t >> 6;
    const int m0 = blockIdx.x * 128;
    const int bn = blockIdx.y;
    const int which = bn / nbn_per;
    const int n0 = (bn % nbn_per) * 128;
    const u16* W = (which == 0) ? W0 : (which == 1) ? W1 : W2;
    OutT* O = (which == 0) ? O0 : (which == 1) ? O1 : O2;

    __shared__ u16 Alds[128 * 32];
    __shared__ u16 Blds[128 * 32];

    const int wm = wave >> 1, wn = wave & 1;
    const int r16 = lane & 15, g4 = lane >> 4;

    f32x4 acc[4][4];
    const f32x4 z = {0.f, 0.f, 0.f, 0.f};
#pragma unroll
    for (int m = 0; m < 4; ++m)
#pragma unroll
        for (int n = 0; n < 4; ++n) acc[m][n] = z;

    for (int k0 = 0; k0 < K; k0 += 32) {
        __syncthreads();
#pragma unroll
        for (int j = 0; j < 2; ++j) {
            int i = j * 256 + t;
            int row = i >> 2, seg = i & 3;
            async16(A + (size_t)(m0 + row) * K + k0 + seg * 8,
                    Alds + (size_t)(j * 256 + wave * 64) * 8);
            async16(W + (size_t)(n0 + row) * K + k0 + seg * 8,
                    Blds + (size_t)(j * 256 + wave * 64) * 8);
        }
        __syncthreads();

        bf16x8 af[4], bfr[4];
#pragma unroll
        for (int m = 0; m < 4; ++m)
            af[m] = *reinterpret_cast<const bf16x8*>(Alds + (wm * 64 + m * 16 + r16) * 32 + g4 * 8);
#pragma unroll
        for (int n = 0; n < 4; ++n)
            bfr[n] = *reinterpret_cast<const bf16x8*>(Blds + (wn * 64 + n * 16 + r16) * 32 + g4 * 8);
#pragma unroll
        for (int m = 0; m < 4; ++m)
#pragma unroll
            for (int n = 0; n < 4; ++n)
                acc[m][n] = mfma32(af[m], bfr[n], acc[m][n]);
    }

    bool vtr = false;
    if constexpr (sizeof(OutT) == 2) vtr = (which == vtr_which);
    if (vtr) {
        if constexpr (sizeof(OutT) == 2) {
#pragma unroll
            for (int m = 0; m < 4; ++m)
#pragma unroll
                for (int n = 0; n < 4; ++n) {
                    int row = m0 + wm * 64 + m * 16 + g4 * 4;
                    int col = n0 + wn * 64 + n * 16 + r16;
                    ushort4 pk;
                    pk.x = f2bf(acc[m][n][0]); pk.y = f2bf(acc[m][n][1]);
                    pk.z = f2bf(acc[m][n][2]); pk.w = f2bf(acc[m][n][3]);
                    size_t addr = ((size_t)((row >> 11) * 16 + (col >> 6)) * 64 + (col & 63)) * 2048
                                  + (row & 2047);
                    *reinterpret_cast<ushort4*>((u16*)O + addr) = pk;
                }
        }
    } else {
#pragma unroll
        for (int m = 0; m < 4; ++m)
#pragma unroll
            for (int n = 0; n < 4; ++n) {
                int row = m0 + wm * 64 + m * 16 + g4 * 4;
                int col = n0 + wn * 64 + n * 16 + r16;
#pragma unroll
                for (int r = 0; r < 4; ++r)
                    store_out(&O[(size_t)(row + r) * 1024 + col], acc[m][n][r]);
            }
    }
}

// ---------------------------------------------------------------------------
// Flash attention, key-split across waves.
// Block = 32 q-rows; 4 waves each own a 16-key strip of each 64-key tile.
// FINITE sentinel (-30000): all-masked strips produce weight-0 partials at
// the merge instead of inf/NaN (the R8 bug: -1e30 + fma-rounding -> exp2(inf)).
// ---------------------------------------------------------------------------
__global__ __launch_bounds__(256, 4) void pma_attn_kernel(
    const u16* __restrict__ Q, const u16* __restrict__ Kp, const u16* __restrict__ Vt,
    const int* __restrict__ seq_lengths, u16* __restrict__ O)
{
    const float SENT = -30000.0f;
    const int bx = blockIdx.x;
    const int T = bx >> 5, bh = bx & 31;
    const int qt = (T & 1) ? (63 - (T >> 1)) : (T >> 1);   // zigzag: mix long/short
    const int h = bh & 15, b = bh >> 4;
    const int q0 = qt * 32;
    const int t = threadIdx.x, lane = t & 63, w = t >> 6;
    const int r16 = lane & 15, g4 = lane >> 4;
    const int seqlen = seq_lengths[b];
    const float L2E = 1.4426950408889634f;

    __shared__ u16 Klds[64 * 64];          // [key][d], 16B-chunk ^= (key&7)
    __shared__ u16 Vlds[64 * 64];          // [d][key], 16B-chunk ^= (d&7)
    __shared__ float2 mlbuf[4][32];
    __shared__ float accbuf[4 * 32 * 36];  // [wave][q][32d + pad4]

    const size_t bbase = (size_t)b * 2048 * 1024;
    const size_t hoff = (size_t)h * 64;
    const u16* Kbp = Kp + bbase + hoff;                       // row stride 1024
    const u16* Vbp = Vt + (size_t)((b * 16 + h) * 64) * 2048; // row stride 2048

    const f32x4 z = {0.f, 0.f, 0.f, 0.f};

    // Q fragments (B-operand): 2 q-sub-blocks x 2 d-chunks
    const size_t qrow0 = bbase + (size_t)(q0 + r16) * 1024 + hoff;
    const bf16x8 qf00 = *reinterpret_cast<const bf16x8*>(Q + qrow0 + g4 * 8);
    const bf16x8 qf01 = *reinterpret_cast<const bf16x8*>(Q + qrow0 + 32 + g4 * 8);
    const bf16x8 qf10 = *reinterpret_cast<const bf16x8*>(Q + qrow0 + 16 * 1024 + g4 * 8);
    const bf16x8 qf11 = *reinterpret_cast<const bf16x8*>(Q + qrow0 + 16 * 1024 + 32 + g4 * 8);

    f32x4 acc[2][4];
#pragma unroll
    for (int qc = 0; qc < 2; ++qc)
#pragma unroll
        for (int f = 0; f < 4; ++f) acc[qc][f] = z;
    float m0 = SENT, m1 = SENT, l0 = 0.f, l1 = 0.f;

    int kmax = q0 + 31;
    if (seqlen - 1 < kmax) kmax = seqlen - 1;
    const int nt = (kmax >> 6) + 1;

    // staging geometry (identical for K and V tiles: 64 rows x 8 chunks)
    const int srow = t >> 3, sseg = t & 7;
    const int kw0 = srow * 64 + ((sseg ^ (srow & 7)) * 8);    // +2048 for row+32
    const u16* kg = Kbp + (size_t)srow * 1024 + sseg * 8;
    const u16* vg = Vbp + (size_t)srow * 2048 + sseg * 8;

    // read offsets (constant per lane, swizzle folded in)
    const int kf0_off = (w * 16 + r16) * 64 + ((g4 ^ (r16 & 7)) * 8);
    const int kf1_off = (w * 16 + r16) * 64 + (((g4 + 4) ^ (r16 & 7)) * 8);
    const int vb_sub = (((2 * w + (g4 >> 1)) ^ (r16 & 7)) * 8) + (g4 & 1) * 4;

    bf16x8 kreg0, kreg1, vreg0, vreg1;
    // prologue: tile 0
    kreg0 = *reinterpret_cast<const bf16x8*>(kg);
    kreg1 = *reinterpret_cast<const bf16x8*>(kg + 32 * 1024);
    vreg0 = *reinterpret_cast<const bf16x8*>(vg);
    vreg1 = *reinterpret_cast<const bf16x8*>(vg + 32 * 2048);
    *reinterpret_cast<bf16x8*>(Klds + kw0)        = kreg0;
    *reinterpret_cast<bf16x8*>(Klds + kw0 + 2048) = kreg1;
    *reinterpret_cast<bf16x8*>(Vlds + kw0)        = vreg0;
    *reinterpret_cast<bf16x8*>(Vlds + kw0 + 2048) = vreg1;
    __syncthreads();

    for (int tt = 0; tt < nt; ++tt) {
        const int t0 = tt << 6;

        if (tt + 1 < nt) {
            const int t0n = t0 + 64;
            kreg0 = *reinterpret_cast<const bf16x8*>(kg + (size_t)t0n * 1024);
            kreg1 = *reinterpret_cast<const bf16x8*>(kg + (size_t)(t0n + 32) * 1024);
            vreg0 = *reinterpret_cast<const bf16x8*>(vg + t0n);
            vreg1 = *reinterpret_cast<const bf16x8*>(vg + 32 * 2048 + t0n);
        }

        // ---- QK^T: strip keys (A) x 32 q (B) ----
        bf16x8 kf0 = *reinterpret_cast<const bf16x8*>(Klds + kf0_off);
        bf16x8 kf1 = *reinterpret_cast<const bf16x8*>(Klds + kf1_off);
        __builtin_amdgcn_s_setprio(1);
        f32x4 s0 = z, s1 = z;
        s0 = mfma32(kf0, qf00, s0); s0 = mfma32(kf1, qf01, s0);
        s1 = mfma32(kf0, qf10, s1); s1 = mfma32(kf1, qf11, s1);
        __builtin_amdgcn_s_setprio(0);

        float sc0[4], sc1[4];
#pragma unroll
        for (int r = 0; r < 4; ++r) { sc0[r] = s0[r]; sc1[r] = s1[r]; }
        if (tt == nt - 1) {
#pragma unroll
            for (int r = 0; r < 4; ++r) {
                const int key = t0 + w * 16 + g4 * 4 + r;
                if (key > q0 + r16      || key >= seqlen) sc0[r] = SENT;
                if (key > q0 + 16 + r16 || key >= seqlen) sc1[r] = SENT;
            }
        }

        // ---- online softmax over this wave's 16-key strip ----
        float mx0 = fmaxf(fmaxf(sc0[0], sc0[1]), fmaxf(sc0[2], sc0[3]));
        float mx1 = fmaxf(fmaxf(sc1[0], sc1[1]), fmaxf(sc1[2], sc1[3]));
        mx0 = fmaxf(mx0, __shfl_xor(mx0, 16, 64));
        mx0 = fmaxf(mx0, __shfl_xor(mx0, 32, 64));
        mx1 = fmaxf(mx1, __shfl_xor(mx1, 16, 64));
        mx1 = fmaxf(mx1, __shfl_xor(mx1, 32, 64));

        const bool nore = __all((mx0 <= m0 + 8.0f) && (mx1 <= m1 + 8.0f));
        float c0 = 1.f, c1 = 1.f;
        if (!nore) {
            const float mo0 = m0, mo1 = m1;
            m0 = fmaxf(m0, mx0); m1 = fmaxf(m1, mx1);
            c0 = exp2f((mo0 - m0) * L2E); c1 = exp2f((mo1 - m1) * L2E);
        }
        const float nb0 = m0 * L2E, nb1 = m1 * L2E;
#pragma unroll
        for (int r = 0; r < 4; ++r) {
            sc0[r] = exp2f(__builtin_fmaf(sc0[r], L2E, -nb0));
            sc1[r] = exp2f(__builtin_fmaf(sc1[r], L2E, -nb1));
        }
        float rs0 = (sc0[0] + sc0[1]) + (sc0[2] + sc0[3]);
        float rs1 = (sc1[0] + sc1[1]) + (sc1[2] + sc1[3]);
        rs0 += __shfl_xor(rs0, 16, 64); rs0 += __shfl_xor(rs0, 32, 64);
        rs1 += __shfl_xor(rs1, 16, 64); rs1 += __shfl_xor(rs1, 32, 64);
        if (nore) { l0 += rs0; l1 += rs1; }
        else {
            l0 = l0 * c0 + rs0; l1 = l1 * c1 + rs1;
            float cr0[4], cr1[4];
#pragma unroll
            for (int r = 0; r < 4; ++r) {
                cr0[r] = __shfl(c0, g4 * 4 + r, 64);
                cr1[r] = __shfl(c1, g4 * 4 + r, 64);
            }
#pragma unroll
            for (int f = 0; f < 4; ++f)
#pragma unroll
                for (int r = 0; r < 4; ++r) {
                    acc[0][f][r] *= cr0[r];
                    acc[1][f][r] *= cr1[r];
                }
        }

        // ---- pack P into A-fragments (registers only) ----
        bf16x4 pa0, pa1;
#pragma unroll
        for (int r = 0; r < 4; ++r) {
            pa0[r] = (short)f2bf_fast(sc0[r]);
            pa1[r] = (short)f2bf_fast(sc1[r]);
        }

        // ---- PV: 16x16x16, K-dim = strip (16) ----
        __builtin_amdgcn_s_setprio(1);
#pragma unroll
        for (int f = 0; f < 4; ++f) {
            bf16x4 vb = *reinterpret_cast<const bf16x4*>(Vlds + (f * 16 + r16) * 64 + vb_sub);
            acc[0][f] = mfma16(pa0, vb, acc[0][f]);
            acc[1][f] = mfma16(pa1, vb, acc[1][f]);
        }
        __builtin_amdgcn_s_setprio(0);
        __syncthreads();

        if (tt + 1 < nt) {
            *reinterpret_cast<bf16x8*>(Klds + kw0)        = kreg0;
            *reinterpret_cast<bf16x8*>(Klds + kw0 + 2048) = kreg1;
            *reinterpret_cast<bf16x8*>(Vlds + kw0)        = vreg0;
            *reinterpret_cast<bf16x8*>(Vlds + kw0 + 2048) = vreg1;
            __syncthreads();
        }
    }

    // ---- merge per-wave key-strip partials ----
    if (g4 == 0) {
        mlbuf[w][r16]      = make_float2(m0, l0);
        mlbuf[w][16 + r16] = make_float2(m1, l1);
    }
    __syncthreads();

    float scl0, scl1;
    {
        float2 a0 = mlbuf[0][r16], a1 = mlbuf[1][r16], a2 = mlbuf[2][r16], a3 = mlbuf[3][r16];
        float ms = fmaxf(fmaxf(a0.x, a1.x), fmaxf(a2.x, a3.x));
        float ls = exp2f((a0.x - ms) * L2E) * a0.y + exp2f((a1.x - ms) * L2E) * a1.y
                 + exp2f((a2.x - ms) * L2E) * a2.y + exp2f((a3.x - ms) * L2E) * a3.y;
        scl0 = exp2f((m0 - ms) * L2E) / ls;
    }
    {
        float2 a0 = mlbuf[0][16 + r16], a1 = mlbuf[1][16 + r16],
               a2 = mlbuf[2][16 + r16], a3 = mlbuf[3][16 + r16];
        float ms = fmaxf(fmaxf(a0.x, a1.x), fmaxf(a2.x, a3.x));
        float ls = exp2f((a0.x - ms) * L2E) * a0.y + exp2f((a1.x - ms) * L2E) * a1.y
                 + exp2f((a2.x - ms) * L2E) * a2.y + exp2f((a3.x - ms) * L2E) * a3.y;
        scl1 = exp2f((m1 - ms) * L2E) / ls;
    }
    float sr0[4], sr1[4];
#pragma unroll
    for (int r = 0; r < 4; ++r) {
        sr0[r] = __shfl(scl0, g4 * 4 + r, 64);
        sr1[r] = __shfl(scl1, g4 * 4 + r, 64);
    }
#pragma unroll
    for (int f = 0; f < 4; ++f)
#pragma unroll
        for (int r = 0; r < 4; ++r) {
            acc[0][f][r] *= sr0[r];
            acc[1][f][r] *= sr1[r];
        }

    const int qrel = w * 8 + (lane >> 3);
    const int dw = (lane & 7) * 4;
#pragma unroll
    for (int dh = 0; dh < 2; ++dh) {
        __syncthreads();
#pragma unroll
        for (int ff = 0; ff < 2; ++ff) {
            const int f = dh * 2 + ff;
#pragma unroll
            for (int r = 0; r < 4; ++r) {
                accbuf[(w * 32 + g4 * 4 + r) * 36 + ff * 16 + r16]      = acc[0][f][r];
                accbuf[(w * 32 + 16 + g4 * 4 + r) * 36 + ff * 16 + r16] = acc[1][f][r];
            }
        }
        __syncthreads();
        f32x4 a0 = *reinterpret_cast<const f32x4*>(&accbuf[(0 * 32 + qrel) * 36 + dw]);
        f32x4 a1 = *reinterpret_cast<const f32x4*>(&accbuf[(1 * 32 + qrel) * 36 + dw]);
        f32x4 a2 = *reinterpret_cast<const f32x4*>(&accbuf[(2 * 32 + qrel) * 36 + dw]);
        f32x4 a3 = *reinterpret_cast<const f32x4*>(&accbuf[(3 * 32 + qrel) * 36 + dw]);
        f32x4 s = (a0 + a1) + (a2 + a3);
        ushort4 o;
        o.x = f2bf(s[0]); o.y = f2bf(s[1]); o.z = f2bf(s[2]); o.w = f2bf(s[3]);
        *reinterpret_cast<ushort4*>(O + bbase + (size_t)(q0 + qrel) * 1024 + hoff + dh * 32 + dw) = o;
    }
}

// ---------------------------------------------------------------------------
extern "C" void kernel_launch(void* const* d_in, const int* in_sizes, int n_in,
                              void* d_out, int out_size, void* d_ws, size_t ws_size,
                              hipStream_t stream) {
    const float* x   = (const float*)d_in[0];
    const int*   sql = (const int*)d_in[1];
    const float* Wq  = (const float*)d_in[2];
    const float* Wk  = (const float*)d_in[3];
    const float* Wv  = (const float*)d_in[4];
    const float* Wo  = (const float*)d_in[5];
    float* out = (float*)d_out;

    const size_t MB = 1024 * 1024;
    char* ws = (char*)d_ws;
    u16* xb   = (u16*)(ws + 0 * MB);
    u16* wqb  = (u16*)(ws + 8 * MB);
    u16* wkb  = (u16*)(ws + 10 * MB);
    u16* wvb  = (u16*)(ws + 12 * MB);
    u16* wob  = (u16*)(ws + 14 * MB);
    u16* Qb   = (u16*)(ws + 16 * MB);
    u16* Kb   = (u16*)(ws + 24 * MB);
    u16* Vtb  = (u16*)(ws + 32 * MB);  // V transposed layout [bh*64+d][2048]
    u16* attb = (u16*)(ws + 40 * MB);

    // 1) convert inputs to bf16 (Wq pre-scaled by 1/8)
    pma_cvt_kernel<<<4096, 256, 0, stream>>>(x, xb, 1048576);
    pma_cvt4_kernel<<<dim3(1024, 4), 256, 0, stream>>>(Wq, Wk, Wv, Wo, wqb);

    // 2) fused QKV projection; V written transposed (vtr_which = 2)
    pma_gemm_bt<u16><<<dim3(32, 24), 256, 0, stream>>>(xb, wqb, wkb, wvb, Qb, Kb, Vtb, 1024, 8, 2);

    // 3) flash attention: 2048 blocks (32-row q-tiles), key-split waves
    pma_attn_kernel<<<2048, 256, 0, stream>>>(Qb, Kb, Vtb, sql, attb);

    // 4) output projection -> d_out (fp32)
    pma_gemm_bt<float><<<dim3(32, 8), 256, 0, stream>>>(attb, wob, wob, wob, out, out, out, 1024, 8, -1);
}

// Round 11
// 125.273 us; speedup vs baseline: 1.5729x; 1.1140x over previous
//
#include <hip/hip_runtime.h>

typedef unsigned short u16;
typedef short bf16x8 __attribute__((ext_vector_type(8)));
typedef float f32x4 __attribute__((ext_vector_type(4)));

#define DEVINL __device__ __forceinline__

// fp32 -> bf16 (round-to-nearest-even), bit-level
DEVINL u16 f2bf(float f) {
    union { float f; unsigned int u; } x;
    x.f = f;
    unsigned int u = x.u;
    unsigned int r = (u + 0x7fffu + ((u >> 16) & 1u)) >> 16;
    return (u16)r;
}

// fast fp32 -> bf16 (round-half-up); used for P (bounded, positive) only
DEVINL u16 f2bf_fast(float f) {
    union { float f; unsigned int u; } x;
    x.f = f;
    return (u16)((x.u + 0x8000u) >> 16);
}

// async global->LDS, 16 bytes per lane.
DEVINL void async16(const u16* g, u16* l) {
    __builtin_amdgcn_global_load_lds(
        (const __attribute__((address_space(1))) void*)g,
        (__attribute__((address_space(3))) void*)l, 16, 0, 0);
}

DEVINL void store_out(u16* p, float v)   { *p = f2bf(v); }
DEVINL void store_out(float* p, float v) { *p = v; }

// ---------------------------------------------------------------------------
// fp32 -> bf16 convert kernels
// ---------------------------------------------------------------------------
__global__ void pma_cvt_kernel(const float* __restrict__ in, u16* __restrict__ out, int n4) {
    int i = blockIdx.x * blockDim.x + threadIdx.x;
    if (i < n4) {
        float4 v = reinterpret_cast<const float4*>(in)[i];
        ushort4 o;
        o.x = f2bf(v.x); o.y = f2bf(v.y); o.z = f2bf(v.z); o.w = f2bf(v.w);
        reinterpret_cast<ushort4*>(out)[i] = o;
    }
}

__global__ void pma_cvt4_kernel(const float* __restrict__ w0, const float* __restrict__ w1,
                                const float* __restrict__ w2, const float* __restrict__ w3,
                                u16* __restrict__ dst) {
    const int wsel = blockIdx.y;
    const float* in = (wsel == 0) ? w0 : (wsel == 1) ? w1 : (wsel == 2) ? w2 : w3;
    u16* out = dst + (size_t)wsel * 1024 * 1024;
    const float s = (wsel == 0) ? 0.125f : 1.0f;   // fold 1/sqrt(64) into Wq
    int i = blockIdx.x * blockDim.x + threadIdx.x;
    float4 v = reinterpret_cast<const float4*>(in)[i];
    ushort4 o;
    o.x = f2bf(v.x * s); o.y = f2bf(v.y * s); o.z = f2bf(v.z * s); o.w = f2bf(v.w * s);
    reinterpret_cast<ushort4*>(out)[i] = o;
}

// ---------------------------------------------------------------------------
// GEMM: O[m][n] = sum_k A[m][k] * W[n][k], bf16 in, f32 acc, 128x128 tile.
// which == vtr_which (bf16 out only): store transposed into [bh*64+d][2048 s].
// skip_kv: for K/V projections (which != 0), skip tiles whose 128 m-rows all
// lie >= seqlen[b] (those keys are masked in attention; outputs never read).
// ---------------------------------------------------------------------------
template <typename OutT>
__global__ __launch_bounds__(256) void pma_gemm_bt(
    const u16* __restrict__ A,
    const u16* __restrict__ W0, const u16* __restrict__ W1, const u16* __restrict__ W2,
    OutT* __restrict__ O0, OutT* __restrict__ O1, OutT* __restrict__ O2,
    int K, int nbn_per, int vtr_which,
    const int* __restrict__ seq_lengths, int skip_kv)
{
    const int t = threadIdx.x;
    const int lane = t & 63, wave = t >> 6;
    const int m0 = blockIdx.x * 128;
    const int bn = blockIdx.y;
    const int which = bn / nbn_per;
    const int n0 = (bn % nbn_per) * 128;

    if (skip_kv && which != 0) {
        if ((m0 & 2047) >= seq_lengths[m0 >> 11]) return;   // block-uniform
    }

    const u16* W = (which == 0) ? W0 : (which == 1) ? W1 : W2;
    OutT* O = (which == 0) ? O0 : (which == 1) ? O1 : O2;

    __shared__ u16 Alds[128 * 32];
    __shared__ u16 Blds[128 * 32];

    const int wm = wave >> 1, wn = wave & 1;
    const int r16 = lane & 15, g4 = lane >> 4;

    f32x4 acc[4][4];
    const f32x4 z = {0.f, 0.f, 0.f, 0.f};
#pragma unroll
    for (int m = 0; m < 4; ++m)
#pragma unroll
        for (int n = 0; n < 4; ++n) acc[m][n] = z;

    for (int k0 = 0; k0 < K; k0 += 32) {
        __syncthreads();
#pragma unroll
        for (int j = 0; j < 2; ++j) {
            int i = j * 256 + t;
            int row = i >> 2, seg = i & 3;
            async16(A + (size_t)(m0 + row) * K + k0 + seg * 8,
                    Alds + (size_t)(j * 256 + wave * 64) * 8);
            async16(W + (size_t)(n0 + row) * K + k0 + seg * 8,
                    Blds + (size_t)(j * 256 + wave * 64) * 8);
        }
        __syncthreads();

        bf16x8 af[4], bfr[4];
#pragma unroll
        for (int m = 0; m < 4; ++m)
            af[m] = *reinterpret_cast<const bf16x8*>(Alds + (wm * 64 + m * 16 + r16) * 32 + g4 * 8);
#pragma unroll
        for (int n = 0; n < 4; ++n)
            bfr[n] = *reinterpret_cast<const bf16x8*>(Blds + (wn * 64 + n * 16 + r16) * 32 + g4 * 8);
#pragma unroll
        for (int m = 0; m < 4; ++m)
#pragma unroll
            for (int n = 0; n < 4; ++n)
                acc[m][n] = __builtin_amdgcn_mfma_f32_16x16x32_bf16(af[m], bfr[n], acc[m][n], 0, 0, 0);
    }

    // epilogue: C/D layout col = lane&15, row = (lane>>4)*4 + reg
    bool vtr = false;
    if constexpr (sizeof(OutT) == 2) vtr = (which == vtr_which);
    if (vtr) {
        if constexpr (sizeof(OutT) == 2) {
#pragma unroll
            for (int m = 0; m < 4; ++m)
#pragma unroll
                for (int n = 0; n < 4; ++n) {
                    int row = m0 + wm * 64 + m * 16 + g4 * 4;
                    int col = n0 + wn * 64 + n * 16 + r16;
                    ushort4 pk;
                    pk.x = f2bf(acc[m][n][0]); pk.y = f2bf(acc[m][n][1]);
                    pk.z = f2bf(acc[m][n][2]); pk.w = f2bf(acc[m][n][3]);
                    size_t addr = ((size_t)((row >> 11) * 16 + (col >> 6)) * 64 + (col & 63)) * 2048
                                  + (row & 2047);
                    *reinterpret_cast<ushort4*>((u16*)O + addr) = pk;
                }
        }
    } else {
#pragma unroll
        for (int m = 0; m < 4; ++m)
#pragma unroll
            for (int n = 0; n < 4; ++n) {
                int row = m0 + wm * 64 + m * 16 + g4 * 4;
                int col = n0 + wn * 64 + n * 16 + r16;
#pragma unroll
                for (int r = 0; r < 4; ++r)
                    store_out(&O[(size_t)(row + r) * 1024 + col], acc[m][n][r]);
            }
    }
}

// ---------------------------------------------------------------------------
// Flash attention (causal + padding), bf16 MFMA, fp32 accumulate.
// R7 structure (proven 59.6 us) + LPT dispatch: longest q-tiles first so
// short blocks backfill the scheduler tail (occupancy was 18%: tail-bound).
// Swapped QK^T: lane owns q-row r16, 16 keys in-register.
// V pre-transposed in global; T13 defer-rescale (THR=8); exp2-domain softmax.
// ---------------------------------------------------------------------------
__global__ __launch_bounds__(256, 4) void pma_attn_kernel(
    const u16* __restrict__ Q, const u16* __restrict__ Kp, const u16* __restrict__ Vt,
    const int* __restrict__ seq_lengths, u16* __restrict__ O)
{
    const int bx = blockIdx.x;
    const int qt = 31 - (bx >> 5);   // LPT: longest (qt=31) blocks dispatch first
    const int bh = bx & 31;
    const int h  = bh & 15;
    const int b  = bh >> 4;
    const int q0 = qt * 64;
    const int t = threadIdx.x, lane = t & 63, w = t >> 6;
    const int r16 = lane & 15, g4 = lane >> 4;
    const int seqlen = seq_lengths[b];
    const float L2E = 1.4426950408889634f;

    __shared__ u16 Klds[64 * 72];    // keys x 64d, stride 72
    __shared__ u16 Vtlds[64 * 72];   // d x keys, stride 72
    __shared__ u16 Plds[64 * 72];    // q-rows x keys, stride 72

    const size_t bbase = (size_t)b * 2048 * 1024;
    const size_t hoff = (size_t)h * 64;
    const size_t vrow0 = (size_t)((b * 16 + h) * 64);

    const f32x4 z = {0.f, 0.f, 0.f, 0.f};
    const int krel = t >> 3;         // 0..31
    const int seg  = t & 7;

    const size_t qrowbase = bbase + (size_t)(q0 + w * 16 + r16) * 1024 + hoff;
    const bf16x8 qf0 = *reinterpret_cast<const bf16x8*>(Q + qrowbase + g4 * 8);
    const bf16x8 qf1 = *reinterpret_cast<const bf16x8*>(Q + qrowbase + 32 + g4 * 8);

    f32x4 acc[4];
#pragma unroll
    for (int f = 0; f < 4; ++f) acc[f] = z;
    float mrow = -1e30f, lrow = 0.f;

    int kmax = q0 + 63;
    if (seqlen - 1 < kmax) kmax = seqlen - 1;
    const int nt = (kmax >> 6) + 1;

    // strength-reduced staging bases (row krel, 8-col segment seg)
    const u16* kbase = Kp + bbase + hoff + (size_t)krel * 1024 + seg * 8;
    const u16* vbase = Vt + (vrow0 + krel) * 2048 + seg * 8;

    bf16x8 kreg[2], vreg[2];

    // ---- prologue: load + store tile 0 ----
#pragma unroll
    for (int j = 0; j < 2; ++j) {
        kreg[j] = *reinterpret_cast<const bf16x8*>(kbase + j * 32 * 1024);
        vreg[j] = *reinterpret_cast<const bf16x8*>(vbase + j * 32 * 2048);
    }
#pragma unroll
    for (int j = 0; j < 2; ++j) {
        const int rr = j * 32 + krel;
        *reinterpret_cast<bf16x8*>(Klds + rr * 72 + seg * 8) = kreg[j];
        *reinterpret_cast<bf16x8*>(Vtlds + rr * 72 + seg * 8) = vreg[j];
    }
    __syncthreads();

    const int qhat = q0 + w * 16 + r16;

    for (int tt = 0; tt < nt; ++tt) {
        const int t0 = tt << 6;

        // ---- issue next tile's global loads (hide under compute) ----
        if (tt + 1 < nt) {
            const int t0n = (tt + 1) << 6;
#pragma unroll
            for (int j = 0; j < 2; ++j) {
                kreg[j] = *reinterpret_cast<const bf16x8*>(kbase + (size_t)t0n * 1024 + j * 32 * 1024);
                vreg[j] = *reinterpret_cast<const bf16x8*>(vbase + t0n + j * 32 * 2048);
            }
        }

        // ---- scores (swapped): lane holds 16 keys for q = r16 ----
        f32x4 sraw[4];
        __builtin_amdgcn_s_setprio(1);
#pragma unroll
        for (int kc = 0; kc < 4; ++kc) {
            bf16x8 kf0 = *reinterpret_cast<const bf16x8*>(Klds + (kc * 16 + r16) * 72 + g4 * 8);
            bf16x8 kf1 = *reinterpret_cast<const bf16x8*>(Klds + (kc * 16 + r16) * 72 + 32 + g4 * 8);
            f32x4 s = z;
            s = __builtin_amdgcn_mfma_f32_16x16x32_bf16(kf0, qf0, s, 0, 0, 0);
            s = __builtin_amdgcn_mfma_f32_16x16x32_bf16(kf1, qf1, s, 0, 0, 0);
            sraw[kc] = s;
        }
        __builtin_amdgcn_s_setprio(0);

        float sc[4][4];
        const bool needmask = (t0 == q0) || (t0 + 64 > seqlen);
        if (needmask) {
#pragma unroll
            for (int kc = 0; kc < 4; ++kc) {
                const int keyb = t0 + kc * 16 + g4 * 4;
#pragma unroll
                for (int r = 0; r < 4; ++r)
                    sc[kc][r] = ((keyb + r > qhat) || (keyb + r >= seqlen)) ? -1e30f : sraw[kc][r];
            }
        } else {
#pragma unroll
            for (int kc = 0; kc < 4; ++kc)
#pragma unroll
                for (int r = 0; r < 4; ++r) sc[kc][r] = sraw[kc][r];
        }

        // ---- online softmax (exp2 domain), T13 defer-rescale ----
        float mx;
        {
            float m0 = fmaxf(fmaxf(sc[0][0], sc[0][1]), fmaxf(sc[0][2], sc[0][3]));
            float m1 = fmaxf(fmaxf(sc[1][0], sc[1][1]), fmaxf(sc[1][2], sc[1][3]));
            float m2 = fmaxf(fmaxf(sc[2][0], sc[2][1]), fmaxf(sc[2][2], sc[2][3]));
            float m3 = fmaxf(fmaxf(sc[3][0], sc[3][1]), fmaxf(sc[3][2], sc[3][3]));
            mx = fmaxf(fmaxf(m0, m1), fmaxf(m2, m3));
        }
        mx = fmaxf(mx, __shfl_xor(mx, 16, 64));
        mx = fmaxf(mx, __shfl_xor(mx, 32, 64));

        const bool norescale = __all(mx <= mrow + 8.0f);  // P bounded by e^8
        float mnew, corr;
        if (norescale) { mnew = mrow; corr = 1.0f; }
        else           { mnew = fmaxf(mrow, mx); corr = exp2f((mrow - mnew) * L2E); }

        const float nb = mnew * L2E;
#pragma unroll
        for (int kc = 0; kc < 4; ++kc)
#pragma unroll
            for (int r = 0; r < 4; ++r)
                sc[kc][r] = exp2f(__builtin_fmaf(sc[kc][r], L2E, -nb));
        float rs;
        {
            float s0 = (sc[0][0] + sc[0][1]) + (sc[0][2] + sc[0][3]);
            float s1 = (sc[1][0] + sc[1][1]) + (sc[1][2] + sc[1][3]);
            float s2 = (sc[2][0] + sc[2][1]) + (sc[2][2] + sc[2][3]);
            float s3 = (sc[3][0] + sc[3][1]) + (sc[3][2] + sc[3][3]);
            rs = (s0 + s1) + (s2 + s3);
        }
        rs += __shfl_xor(rs, 16, 64);
        rs += __shfl_xor(rs, 32, 64);
        lrow = lrow * corr + rs;
        mrow = mnew;

        // ---- write P (bf16) 4x b64 ----
#pragma unroll
        for (int kc = 0; kc < 4; ++kc) {
            ushort4 pk;
            pk.x = f2bf_fast(sc[kc][0]); pk.y = f2bf_fast(sc[kc][1]);
            pk.z = f2bf_fast(sc[kc][2]); pk.w = f2bf_fast(sc[kc][3]);
            *reinterpret_cast<ushort4*>(Plds + (w * 16 + r16) * 72 + kc * 16 + g4 * 4) = pk;
        }

        // ---- rescale acc (skipped when max stable: the common case) ----
        if (!norescale) {
            float cr0 = __shfl(corr, g4 * 4 + 0, 64);
            float cr1 = __shfl(corr, g4 * 4 + 1, 64);
            float cr2 = __shfl(corr, g4 * 4 + 2, 64);
            float cr3 = __shfl(corr, g4 * 4 + 3, 64);
#pragma unroll
            for (int f = 0; f < 4; ++f) {
                f32x4 a = acc[f];
                a[0] *= cr0; a[1] *= cr1; a[2] *= cr2; a[3] *= cr3;
                acc[f] = a;
            }
        }

        // ---- PV: O[q][d] += P[q][k] * V[k][d] ----
        __builtin_amdgcn_s_setprio(1);
#pragma unroll
        for (int kc2 = 0; kc2 < 2; ++kc2) {
            bf16x8 pa = *reinterpret_cast<const bf16x8*>(Plds + (w * 16 + r16) * 72 + kc2 * 32 + g4 * 8);
#pragma unroll
            for (int f = 0; f < 4; ++f) {
                bf16x8 vb = *reinterpret_cast<const bf16x8*>(Vtlds + (f * 16 + r16) * 72 + kc2 * 32 + g4 * 8);
                acc[f] = __builtin_amdgcn_mfma_f32_16x16x32_bf16(pa, vb, acc[f], 0, 0, 0);
            }
        }
        __builtin_amdgcn_s_setprio(0);
        __syncthreads();

        // ---- store next tile from regs ----
        if (tt + 1 < nt) {
#pragma unroll
            for (int j = 0; j < 2; ++j) {
                const int rr = j * 32 + krel;
                *reinterpret_cast<bf16x8*>(Klds + rr * 72 + seg * 8) = kreg[j];
                *reinterpret_cast<bf16x8*>(Vtlds + rr * 72 + seg * 8) = vreg[j];
            }
            __syncthreads();
        }
    }

    // ---- epilogue: normalize and store ----
    {
        float lr0 = __shfl(lrow, g4 * 4 + 0, 64);
        float lr1 = __shfl(lrow, g4 * 4 + 1, 64);
        float lr2 = __shfl(lrow, g4 * 4 + 2, 64);
        float lr3 = __shfl(lrow, g4 * 4 + 3, 64);
        float lr[4] = {lr0, lr1, lr2, lr3};
#pragma unroll
        for (int f = 0; f < 4; ++f)
#pragma unroll
            for (int r = 0; r < 4; ++r) {
                int sr = q0 + w * 16 + g4 * 4 + r;
                float o = acc[f][r] / lr[r];
                O[bbase + (size_t)sr * 1024 + hoff + f * 16 + r16] = f2bf(o);
            }
    }
}

// ---------------------------------------------------------------------------
extern "C" void kernel_launch(void* const* d_in, const int* in_sizes, int n_in,
                              void* d_out, int out_size, void* d_ws, size_t ws_size,
                              hipStream_t stream) {
    const float* x   = (const float*)d_in[0];
    const int*   sql = (const int*)d_in[1];
    const float* Wq  = (const float*)d_in[2];
    const float* Wk  = (const float*)d_in[3];
    const float* Wv  = (const float*)d_in[4];
    const float* Wo  = (const float*)d_in[5];
    float* out = (float*)d_out;

    const size_t MB = 1024 * 1024;
    char* ws = (char*)d_ws;
    u16* xb   = (u16*)(ws + 0 * MB);
    u16* wqb  = (u16*)(ws + 8 * MB);
    u16* wkb  = (u16*)(ws + 10 * MB);
    u16* wvb  = (u16*)(ws + 12 * MB);
    u16* wob  = (u16*)(ws + 14 * MB);
    u16* Qb   = (u16*)(ws + 16 * MB);
    u16* Kb   = (u16*)(ws + 24 * MB);
    u16* Vtb  = (u16*)(ws + 32 * MB);  // V transposed layout [bh*64+d][2048]
    u16* attb = (u16*)(ws + 40 * MB);

    // 1) convert inputs to bf16 (Wq pre-scaled by 1/8)
    pma_cvt_kernel<<<4096, 256, 0, stream>>>(x, xb, 1048576);
    pma_cvt4_kernel<<<dim3(1024, 4), 256, 0, stream>>>(Wq, Wk, Wv, Wo, wqb);

    // 2) fused QKV projection; V transposed (vtr_which=2); skip K/V tiles >= seqlen
    pma_gemm_bt<u16><<<dim3(32, 24), 256, 0, stream>>>(xb, wqb, wkb, wvb, Qb, Kb, Vtb,
                                                       1024, 8, 2, sql, 1);

    // 3) flash attention: 1024 blocks, LPT dispatch (longest first)
    pma_attn_kernel<<<1024, 256, 0, stream>>>(Qb, Kb, Vtb, sql, attb);

    // 4) output projection -> d_out (fp32)
    pma_gemm_bt<float><<<dim3(32, 8), 256, 0, stream>>>(attb, wob, wob, wob, out, out, out,
                                                        1024, 8, -1, sql, 0);
}

// Round 12
// 120.763 us; speedup vs baseline: 1.6316x; 1.0373x over previous
//
#include <hip/hip_runtime.h>

typedef unsigned short u16;
typedef short bf16x8 __attribute__((ext_vector_type(8)));
typedef float f32x4 __attribute__((ext_vector_type(4)));

#define DEVINL __device__ __forceinline__

// fp32 -> bf16 (round-to-nearest-even), bit-level
DEVINL u16 f2bf(float f) {
    union { float f; unsigned int u; } x;
    x.f = f;
    unsigned int u = x.u;
    unsigned int r = (u + 0x7fffu + ((u >> 16) & 1u)) >> 16;
    return (u16)r;
}

// fast fp32 -> bf16 (round-half-up); used for P (bounded, positive) only
DEVINL u16 f2bf_fast(float f) {
    union { float f; unsigned int u; } x;
    x.f = f;
    return (u16)((x.u + 0x8000u) >> 16);
}

// async global->LDS, 16 bytes per lane.
DEVINL void async16(const u16* g, u16* l) {
    __builtin_amdgcn_global_load_lds(
        (const __attribute__((address_space(1))) void*)g,
        (__attribute__((address_space(3))) void*)l, 16, 0, 0);
}

DEVINL void store_out(u16* p, float v)   { *p = f2bf(v); }
DEVINL void store_out(float* p, float v) { *p = v; }

// ---------------------------------------------------------------------------
// fp32 -> bf16 convert kernels
// ---------------------------------------------------------------------------
__global__ void pma_cvt_kernel(const float* __restrict__ in, u16* __restrict__ out, int n4) {
    int i = blockIdx.x * blockDim.x + threadIdx.x;
    if (i < n4) {
        float4 v = reinterpret_cast<const float4*>(in)[i];
        ushort4 o;
        o.x = f2bf(v.x); o.y = f2bf(v.y); o.z = f2bf(v.z); o.w = f2bf(v.w);
        reinterpret_cast<ushort4*>(out)[i] = o;
    }
}

__global__ void pma_cvt4_kernel(const float* __restrict__ w0, const float* __restrict__ w1,
                                const float* __restrict__ w2, const float* __restrict__ w3,
                                u16* __restrict__ dst) {
    const int wsel = blockIdx.y;
    const float* in = (wsel == 0) ? w0 : (wsel == 1) ? w1 : (wsel == 2) ? w2 : w3;
    u16* out = dst + (size_t)wsel * 1024 * 1024;
    const float s = (wsel == 0) ? 0.125f : 1.0f;   // fold 1/sqrt(64) into Wq
    int i = blockIdx.x * blockDim.x + threadIdx.x;
    float4 v = reinterpret_cast<const float4*>(in)[i];
    ushort4 o;
    o.x = f2bf(v.x * s); o.y = f2bf(v.y * s); o.z = f2bf(v.z * s); o.w = f2bf(v.w * s);
    reinterpret_cast<ushort4*>(out)[i] = o;
}

// ---------------------------------------------------------------------------
// GEMM: O[m][n] = sum_k A[m][k] * W[n][k], bf16 in, f32 acc, 128x128 tile.
// which == vtr_which (bf16 out only): store transposed into [bh*64+d][2048 s].
// skip_kv: skip K/V tiles whose m-rows all lie >= seqlen[b].
// ---------------------------------------------------------------------------
template <typename OutT>
__global__ __launch_bounds__(256) void pma_gemm_bt(
    const u16* __restrict__ A,
    const u16* __restrict__ W0, const u16* __restrict__ W1, const u16* __restrict__ W2,
    OutT* __restrict__ O0, OutT* __restrict__ O1, OutT* __restrict__ O2,
    int K, int nbn_per, int vtr_which,
    const int* __restrict__ seq_lengths, int skip_kv)
{
    const int t = threadIdx.x;
    const int lane = t & 63, wave = t >> 6;
    const int m0 = blockIdx.x * 128;
    const int bn = blockIdx.y;
    const int which = bn / nbn_per;
    const int n0 = (bn % nbn_per) * 128;

    if (skip_kv && which != 0) {
        if ((m0 & 2047) >= seq_lengths[m0 >> 11]) return;   // block-uniform
    }

    const u16* W = (which == 0) ? W0 : (which == 1) ? W1 : W2;
    OutT* O = (which == 0) ? O0 : (which == 1) ? O1 : O2;

    __shared__ u16 Alds[128 * 32];
    __shared__ u16 Blds[128 * 32];

    const int wm = wave >> 1, wn = wave & 1;
    const int r16 = lane & 15, g4 = lane >> 4;

    f32x4 acc[4][4];
    const f32x4 z = {0.f, 0.f, 0.f, 0.f};
#pragma unroll
    for (int m = 0; m < 4; ++m)
#pragma unroll
        for (int n = 0; n < 4; ++n) acc[m][n] = z;

    for (int k0 = 0; k0 < K; k0 += 32) {
        __syncthreads();
#pragma unroll
        for (int j = 0; j < 2; ++j) {
            int i = j * 256 + t;
            int row = i >> 2, seg = i & 3;
            async16(A + (size_t)(m0 + row) * K + k0 + seg * 8,
                    Alds + (size_t)(j * 256 + wave * 64) * 8);
            async16(W + (size_t)(n0 + row) * K + k0 + seg * 8,
                    Blds + (size_t)(j * 256 + wave * 64) * 8);
        }
        __syncthreads();

        bf16x8 af[4], bfr[4];
#pragma unroll
        for (int m = 0; m < 4; ++m)
            af[m] = *reinterpret_cast<const bf16x8*>(Alds + (wm * 64 + m * 16 + r16) * 32 + g4 * 8);
#pragma unroll
        for (int n = 0; n < 4; ++n)
            bfr[n] = *reinterpret_cast<const bf16x8*>(Blds + (wn * 64 + n * 16 + r16) * 32 + g4 * 8);
#pragma unroll
        for (int m = 0; m < 4; ++m)
#pragma unroll
            for (int n = 0; n < 4; ++n)
                acc[m][n] = __builtin_amdgcn_mfma_f32_16x16x32_bf16(af[m], bfr[n], acc[m][n], 0, 0, 0);
    }

    // epilogue: C/D layout col = lane&15, row = (lane>>4)*4 + reg
    bool vtr = false;
    if constexpr (sizeof(OutT) == 2) vtr = (which == vtr_which);
    if (vtr) {
        if constexpr (sizeof(OutT) == 2) {
#pragma unroll
            for (int m = 0; m < 4; ++m)
#pragma unroll
                for (int n = 0; n < 4; ++n) {
                    int row = m0 + wm * 64 + m * 16 + g4 * 4;
                    int col = n0 + wn * 64 + n * 16 + r16;
                    ushort4 pk;
                    pk.x = f2bf(acc[m][n][0]); pk.y = f2bf(acc[m][n][1]);
                    pk.z = f2bf(acc[m][n][2]); pk.w = f2bf(acc[m][n][3]);
                    size_t addr = ((size_t)((row >> 11) * 16 + (col >> 6)) * 64 + (col & 63)) * 2048
                                  + (row & 2047);
                    *reinterpret_cast<ushort4*>((u16*)O + addr) = pk;
                }
        }
    } else {
#pragma unroll
        for (int m = 0; m < 4; ++m)
#pragma unroll
            for (int n = 0; n < 4; ++n) {
                int row = m0 + wm * 64 + m * 16 + g4 * 4;
                int col = n0 + wn * 64 + n * 16 + r16;
#pragma unroll
                for (int r = 0; r < 4; ++r)
                    store_out(&O[(size_t)(row + r) * 1024 + col], acc[m][n][r]);
            }
    }
}

// ---------------------------------------------------------------------------
// Flash attention (causal + padding), bf16 MFMA, fp32 accumulate.
// R11 structure + double-buffered K/V LDS (XOR-16B-chunk swizzle, no pads):
// ONE __syncthreads per tile. LDS = 2x8K (K) + 2x8K (V) + 8K (P) = 40 KB
// exactly -> 4 blocks/CU. LPT dispatch (longest q-tiles first).
// ---------------------------------------------------------------------------
__global__ __launch_bounds__(256, 4) void pma_attn_kernel(
    const u16* __restrict__ Q, const u16* __restrict__ Kp, const u16* __restrict__ Vt,
    const int* __restrict__ seq_lengths, u16* __restrict__ O)
{
    const int bx = blockIdx.x;
    const int qt = 31 - (bx >> 5);   // LPT: longest (qt=31) blocks dispatch first
    const int bh = bx & 31;
    const int h  = bh & 15;
    const int b  = bh >> 4;
    const int q0 = qt * 64;
    const int t = threadIdx.x, lane = t & 63, w = t >> 6;
    const int r16 = lane & 15, g4 = lane >> 4;
    const int seqlen = seq_lengths[b];
    const float L2E = 1.4426950408889634f;

    // double-buffered K/V + P; all [row][64] u16 with 16B-chunk XOR swizzle
    __shared__ u16 Klds[2 * 64 * 64];
    __shared__ u16 Vlds[2 * 64 * 64];
    __shared__ u16 Plds[64 * 64];

    const size_t bbase = (size_t)b * 2048 * 1024;
    const size_t hoff = (size_t)h * 64;
    const size_t vrow0 = (size_t)((b * 16 + h) * 64);

    const f32x4 z = {0.f, 0.f, 0.f, 0.f};
    const int krel = t >> 3;         // 0..31
    const int seg  = t & 7;

    const size_t qrowbase = bbase + (size_t)(q0 + w * 16 + r16) * 1024 + hoff;
    const bf16x8 qf0 = *reinterpret_cast<const bf16x8*>(Q + qrowbase + g4 * 8);
    const bf16x8 qf1 = *reinterpret_cast<const bf16x8*>(Q + qrowbase + 32 + g4 * 8);

    f32x4 acc[4];
#pragma unroll
    for (int f = 0; f < 4; ++f) acc[f] = z;
    float mrow = -1e30f, lrow = 0.f;

    int kmax = q0 + 63;
    if (seqlen - 1 < kmax) kmax = seqlen - 1;
    const int nt = (kmax >> 6) + 1;

    // staging: row = j*32 + krel, chunk = seg; phys chunk = seg ^ (row&7)
    const u16* kbase = Kp + bbase + hoff + (size_t)krel * 1024 + seg * 8;
    const u16* vbase = Vt + (vrow0 + krel) * 2048 + seg * 8;
    const int stw = krel * 64 + ((seg ^ (krel & 7)) * 8);   // +2048 u16 for j=1

    // K read offsets (lane-constant part): row = kc*16 + r16, chunks g4, g4+4
    const int r7 = r16 & 7;
    const int kread_lo = r16 * 64 + ((g4 ^ r7) * 8);
    const int kread_hi = r16 * 64 + (((g4 + 4) ^ r7) * 8);
    // P offsets: row = w*16 + r16
    const int prow = (w * 16 + r16) * 64;

    bf16x8 kreg[2], vreg[2];

    // ---- prologue: load + store tile 0 into buffer 0 ----
#pragma unroll
    for (int j = 0; j < 2; ++j) {
        kreg[j] = *reinterpret_cast<const bf16x8*>(kbase + j * 32 * 1024);
        vreg[j] = *reinterpret_cast<const bf16x8*>(vbase + j * 32 * 2048);
    }
#pragma unroll
    for (int j = 0; j < 2; ++j) {
        *reinterpret_cast<bf16x8*>(Klds + stw + j * 2048) = kreg[j];
        *reinterpret_cast<bf16x8*>(Vlds + stw + j * 2048) = vreg[j];
    }
    __syncthreads();

    const int qhat = q0 + w * 16 + r16;

    for (int tt = 0; tt < nt; ++tt) {
        const int t0 = tt << 6;
        const int dbo = (tt & 1) << 12;          // current buffer (u16 offset)
        const int dbn = 4096 - dbo;              // next buffer

        // ---- issue next tile's global loads (hide under compute) ----
        if (tt + 1 < nt) {
            const int t0n = (tt + 1) << 6;
#pragma unroll
            for (int j = 0; j < 2; ++j) {
                kreg[j] = *reinterpret_cast<const bf16x8*>(kbase + (size_t)t0n * 1024 + j * 32 * 1024);
                vreg[j] = *reinterpret_cast<const bf16x8*>(vbase + t0n + j * 32 * 2048);
            }
        }

        // ---- scores (swapped): lane holds 16 keys for q = r16 ----
        f32x4 sraw[4];
        __builtin_amdgcn_s_setprio(1);
#pragma unroll
        for (int kc = 0; kc < 4; ++kc) {
            bf16x8 kf0 = *reinterpret_cast<const bf16x8*>(Klds + dbo + kc * 1024 + kread_lo);
            bf16x8 kf1 = *reinterpret_cast<const bf16x8*>(Klds + dbo + kc * 1024 + kread_hi);
            f32x4 s = z;
            s = __builtin_amdgcn_mfma_f32_16x16x32_bf16(kf0, qf0, s, 0, 0, 0);
            s = __builtin_amdgcn_mfma_f32_16x16x32_bf16(kf1, qf1, s, 0, 0, 0);
            sraw[kc] = s;
        }
        __builtin_amdgcn_s_setprio(0);

        float sc[4][4];
        const bool needmask = (t0 == q0) || (t0 + 64 > seqlen);
        if (needmask) {
#pragma unroll
            for (int kc = 0; kc < 4; ++kc) {
                const int keyb = t0 + kc * 16 + g4 * 4;
#pragma unroll
                for (int r = 0; r < 4; ++r)
                    sc[kc][r] = ((keyb + r > qhat) || (keyb + r >= seqlen)) ? -1e30f : sraw[kc][r];
            }
        } else {
#pragma unroll
            for (int kc = 0; kc < 4; ++kc)
#pragma unroll
                for (int r = 0; r < 4; ++r) sc[kc][r] = sraw[kc][r];
        }

        // ---- online softmax (exp2 domain), T13 defer-rescale ----
        float mx;
        {
            float m0 = fmaxf(fmaxf(sc[0][0], sc[0][1]), fmaxf(sc[0][2], sc[0][3]));
            float m1 = fmaxf(fmaxf(sc[1][0], sc[1][1]), fmaxf(sc[1][2], sc[1][3]));
            float m2 = fmaxf(fmaxf(sc[2][0], sc[2][1]), fmaxf(sc[2][2], sc[2][3]));
            float m3 = fmaxf(fmaxf(sc[3][0], sc[3][1]), fmaxf(sc[3][2], sc[3][3]));
            mx = fmaxf(fmaxf(m0, m1), fmaxf(m2, m3));
        }
        mx = fmaxf(mx, __shfl_xor(mx, 16, 64));
        mx = fmaxf(mx, __shfl_xor(mx, 32, 64));

        const bool norescale = __all(mx <= mrow + 8.0f);  // P bounded by e^8
        float mnew, corr;
        if (norescale) { mnew = mrow; corr = 1.0f; }
        else           { mnew = fmaxf(mrow, mx); corr = exp2f((mrow - mnew) * L2E); }

        const float nb = mnew * L2E;
#pragma unroll
        for (int kc = 0; kc < 4; ++kc)
#pragma unroll
            for (int r = 0; r < 4; ++r)
                sc[kc][r] = exp2f(__builtin_fmaf(sc[kc][r], L2E, -nb));
        float rs;
        {
            float s0 = (sc[0][0] + sc[0][1]) + (sc[0][2] + sc[0][3]);
            float s1 = (sc[1][0] + sc[1][1]) + (sc[1][2] + sc[1][3]);
            float s2 = (sc[2][0] + sc[2][1]) + (sc[2][2] + sc[2][3]);
            float s3 = (sc[3][0] + sc[3][1]) + (sc[3][2] + sc[3][3]);
            rs = (s0 + s1) + (s2 + s3);
        }
        rs += __shfl_xor(rs, 16, 64);
        rs += __shfl_xor(rs, 32, 64);
        lrow = lrow * corr + rs;
        mrow = mnew;

        // ---- write P (bf16) 4x b64; 16B-chunk XOR layout ----
#pragma unroll
        for (int kc = 0; kc < 4; ++kc) {
            ushort4 pk;
            pk.x = f2bf_fast(sc[kc][0]); pk.y = f2bf_fast(sc[kc][1]);
            pk.z = f2bf_fast(sc[kc][2]); pk.w = f2bf_fast(sc[kc][3]);
            const int phys16 = (kc * 2 + (g4 >> 1)) ^ r7;
            *reinterpret_cast<ushort4*>(Plds + prow + phys16 * 8 + (g4 & 1) * 4) = pk;
        }

        // ---- rescale acc (skipped when max stable: the common case) ----
        if (!norescale) {
            float cr0 = __shfl(corr, g4 * 4 + 0, 64);
            float cr1 = __shfl(corr, g4 * 4 + 1, 64);
            float cr2 = __shfl(corr, g4 * 4 + 2, 64);
            float cr3 = __shfl(corr, g4 * 4 + 3, 64);
#pragma unroll
            for (int f = 0; f < 4; ++f) {
                f32x4 a = acc[f];
                a[0] *= cr0; a[1] *= cr1; a[2] *= cr2; a[3] *= cr3;
                acc[f] = a;
            }
        }

        // ---- PV: O[q][d] += P[q][k] * V[k][d] ----
        __builtin_amdgcn_s_setprio(1);
#pragma unroll
        for (int kc2 = 0; kc2 < 2; ++kc2) {
            bf16x8 pa = *reinterpret_cast<const bf16x8*>(Plds + prow + (((kc2 * 4 + g4) ^ r7) * 8));
#pragma unroll
            for (int f = 0; f < 4; ++f) {
                bf16x8 vb = *reinterpret_cast<const bf16x8*>(
                    Vlds + dbo + (f * 16 + r16) * 64 + (((kc2 * 4 + g4) ^ r7) * 8));
                acc[f] = __builtin_amdgcn_mfma_f32_16x16x32_bf16(pa, vb, acc[f], 0, 0, 0);
            }
        }
        __builtin_amdgcn_s_setprio(0);

        // ---- write next tile into the OTHER buffer; single barrier ----
        if (tt + 1 < nt) {
#pragma unroll
            for (int j = 0; j < 2; ++j) {
                *reinterpret_cast<bf16x8*>(Klds + dbn + stw + j * 2048) = kreg[j];
                *reinterpret_cast<bf16x8*>(Vlds + dbn + stw + j * 2048) = vreg[j];
            }
            __syncthreads();
        }
    }

    // ---- epilogue: normalize and store ----
    {
        float lr0 = __shfl(lrow, g4 * 4 + 0, 64);
        float lr1 = __shfl(lrow, g4 * 4 + 1, 64);
        float lr2 = __shfl(lrow, g4 * 4 + 2, 64);
        float lr3 = __shfl(lrow, g4 * 4 + 3, 64);
        float lr[4] = {lr0, lr1, lr2, lr3};
#pragma unroll
        for (int f = 0; f < 4; ++f)
#pragma unroll
            for (int r = 0; r < 4; ++r) {
                int sr = q0 + w * 16 + g4 * 4 + r;
                float o = acc[f][r] / lr[r];
                O[bbase + (size_t)sr * 1024 + hoff + f * 16 + r16] = f2bf(o);
            }
    }
}

// ---------------------------------------------------------------------------
extern "C" void kernel_launch(void* const* d_in, const int* in_sizes, int n_in,
                              void* d_out, int out_size, void* d_ws, size_t ws_size,
                              hipStream_t stream) {
    const float* x   = (const float*)d_in[0];
    const int*   sql = (const int*)d_in[1];
    const float* Wq  = (const float*)d_in[2];
    const float* Wk  = (const float*)d_in[3];
    const float* Wv  = (const float*)d_in[4];
    const float* Wo  = (const float*)d_in[5];
    float* out = (float*)d_out;

    const size_t MB = 1024 * 1024;
    char* ws = (char*)d_ws;
    u16* xb   = (u16*)(ws + 0 * MB);
    u16* wqb  = (u16*)(ws + 8 * MB);
    u16* wkb  = (u16*)(ws + 10 * MB);
    u16* wvb  = (u16*)(ws + 12 * MB);
    u16* wob  = (u16*)(ws + 14 * MB);
    u16* Qb   = (u16*)(ws + 16 * MB);
    u16* Kb   = (u16*)(ws + 24 * MB);
    u16* Vtb  = (u16*)(ws + 32 * MB);  // V transposed layout [bh*64+d][2048]
    u16* attb = (u16*)(ws + 40 * MB);

    // 1) convert inputs to bf16 (Wq pre-scaled by 1/8)
    pma_cvt_kernel<<<4096, 256, 0, stream>>>(x, xb, 1048576);
    pma_cvt4_kernel<<<dim3(1024, 4), 256, 0, stream>>>(Wq, Wk, Wv, Wo, wqb);

    // 2) fused QKV projection; V transposed (vtr_which=2); skip K/V tiles >= seqlen
    pma_gemm_bt<u16><<<dim3(32, 24), 256, 0, stream>>>(xb, wqb, wkb, wvb, Qb, Kb, Vtb,
                                                       1024, 8, 2, sql, 1);

    // 3) flash attention: 1024 blocks, LPT, double-buffered single-barrier
    pma_attn_kernel<<<1024, 256, 0, stream>>>(Qb, Kb, Vtb, sql, attb);

    // 4) output projection -> d_out (fp32)
    pma_gemm_bt<float><<<dim3(32, 8), 256, 0, stream>>>(attb, wob, wob, wob, out, out, out,
                                                        1024, 8, -1, sql, 0);
}